// Round 8
// baseline (290.943 us; speedup 1.0000x reference)
//
#include <hip/hip_runtime.h>

#define N_E   1024
#define EDIM  256
#define BB    16
#define TT    1024
#define NROW  (BB*TT)        /* 16384 */
#define NCOL  1025
#define NPAD  1152           /* 9*128 */
#define PERS  (0.1f/1024.0f)
#define EPSC  (1e-6f/1024.0f)

/* d_out layout (float32): z_q [0,4194304) | loss 4194304 | ind [4194305,+16384) | v 4210689 */
#define OUT_LOSS 4194304
#define OUT_IDX  4194305
#define OUT_V    4210689

/* ws layout (bytes) */
#define WS_ZB   0ull                               /* 16384*256*2  = 8388608  */
#define WS_BBF  8388608ull                         /* 1152*256*2   = 589824   */
#define WS_BSQ  8978432ull                         /* 1152*4       = 4608     */
#define WS_E    8983552ull                         /* 16384*1152*4 = 75497472 */
#define WS_IND  84481024ull                        /* 16384*4                 */
#define WS_PART 84546560ull                        /* 16384*4                 */
#define WS_Q    84612096ull                        /* 16384*1024*2 = 33554432 */

typedef __attribute__((ext_vector_type(8))) short short8;
typedef __attribute__((ext_vector_type(4))) float floatx4;

__device__ __forceinline__ unsigned short f2bf(float f) {
    unsigned int u = __float_as_uint(f);
    u = (u + 0x7fffu + ((u >> 16) & 1u)) >> 16;   /* RNE */
    return (unsigned short)u;
}

/* ---------------- K0: convert z/book -> bf16, compute bsq (fp32) ---------------- */
__global__ __launch_bounds__(256) void k0_prep(const float* __restrict__ z,
                                               const float* __restrict__ book,
                                               unsigned short* __restrict__ zb,
                                               unsigned short* __restrict__ bb,
                                               float* __restrict__ bsq) {
    int bx = blockIdx.x, tid = threadIdx.x;
    if (bx < 4096) {                     /* z: 4096 blocks * 256 thr * 4 floats */
        float4 v = ((const float4*)z)[bx * 256 + tid];
        size_t o = ((size_t)bx * 256 + tid) * 4;
        zb[o + 0] = f2bf(v.x); zb[o + 1] = f2bf(v.y);
        zb[o + 2] = f2bf(v.z); zb[o + 3] = f2bf(v.w);
    } else {                             /* book rows, padded to 1152 with zeros */
        int row = bx - 4096;             /* 0..1151 */
        float v = (row < NCOL) ? book[(size_t)row * EDIM + tid] : 0.0f;
        bb[(size_t)row * EDIM + tid] = f2bf(v);
        __shared__ float sd[256];
        sd[tid] = v * v;
        __syncthreads();
        for (int s = 128; s > 0; s >>= 1) { if (tid < s) sd[tid] += sd[tid + s]; __syncthreads(); }
        if (tid == 0) bsq[row] = sd[0];
    }
}

/* ---------------- K1: e[r][n] = bsq[n] - 2 * dot(z[r], book[n])  (bf16 MFMA) ---- */
__global__ __launch_bounds__(256) void k1_gemm(const unsigned short* __restrict__ zb,
                                               const unsigned short* __restrict__ bb,
                                               const float* __restrict__ bsq,
                                               float* __restrict__ e) {
    int tid = threadIdx.x;
    int lane = tid & 63, w = tid >> 6;
    int mBase = blockIdx.x * 128 + (w >> 1) * 64;
    int nBase = blockIdx.y * 128 + (w & 1) * 64;
    int r = lane & 15, q = lane >> 4;

    floatx4 acc[4][4];
    #pragma unroll
    for (int i = 0; i < 4; i++)
        #pragma unroll
        for (int j = 0; j < 4; j++) acc[i][j] = (floatx4){0.f, 0.f, 0.f, 0.f};

    const short8* A = (const short8*)zb;   /* row stride 256 bf16 = 32 short8 */
    const short8* Bm = (const short8*)bb;

    #pragma unroll
    for (int ks = 0; ks < 8; ks++) {
        int k8 = ks * 4 + q;               /* short8 index in row: (ks*32+q*8)/8 */
        short8 a[4], b[4];
        #pragma unroll
        for (int i = 0; i < 4; i++) a[i] = A[(size_t)(mBase + i * 16 + r) * 32 + k8];
        #pragma unroll
        for (int j = 0; j < 4; j++) b[j] = Bm[(size_t)(nBase + j * 16 + r) * 32 + k8];
        #pragma unroll
        for (int i = 0; i < 4; i++)
            #pragma unroll
            for (int j = 0; j < 4; j++)
                acc[i][j] = __builtin_amdgcn_mfma_f32_16x16x32_bf16(a[i], b[j], acc[i][j], 0, 0, 0);
    }

    float bsql[4];
    #pragma unroll
    for (int j = 0; j < 4; j++) bsql[j] = bsq[nBase + j * 16 + r];

    #pragma unroll
    for (int i = 0; i < 4; i++)
        #pragma unroll
        for (int rr = 0; rr < 4; rr++) {
            int m = mBase + i * 16 + q * 4 + rr;
            float* erow = e + (size_t)m * NPAD;
            #pragma unroll
            for (int j = 0; j < 4; j++)
                erow[nBase + j * 16 + r] = fmaf(-2.0f, acc[i][j][rr], bsql[j]);
        }
}

/* ---------------- K1b: q16[row][c] = clamp(floor((e[c+1]-e[c])/P), -1, 1023) ----
   col 1023 forced to 0 (reference compares ind=1023 with itself -> m=0).      */
__global__ __launch_bounds__(256) void k1b_q(const float* __restrict__ e,
                                             short* __restrict__ q16) {
    int row = blockIdx.x, tid = threadIdx.x;
    const float* er = e + (size_t)row * NPAD;
    short* qr = q16 + (size_t)row * 1024;
    const float QS = 1.0f / PERS;
    #pragma unroll
    for (int i = 0; i < 4; i++) {
        int c = tid + i * 256;
        float a = er[c], bv = er[c + 1];
        float x = (bv - a) * QS;
        int qv = (x >= 0.0f) ? min((int)x, 1023) : -1;
        if (c == 1023) qv = 0;
        qr[c] = (short)qv;
    }
}

/* ---------------- K2a: fp32 argmin of d[b,0,:] (reference-style) ---------------- */
__global__ __launch_bounds__(256) void k2a_argmin(const float* __restrict__ z,
                                                  const float* __restrict__ book,
                                                  const float* __restrict__ bsq,
                                                  int* __restrict__ wind) {
    int b = blockIdx.x, tid = threadIdx.x;
    int lane = tid & 63, w = tid >> 6;

    const float4* zr = (const float4*)(z + (size_t)b * TT * EDIM);  /* t=0 row */
    float4 zv = zr[lane];
    float s = zv.x * zv.x + zv.y * zv.y + zv.z * zv.z + zv.w * zv.w;
    #pragma unroll
    for (int off = 32; off; off >>= 1) s += __shfl_xor(s, off, 64);
    float zsq = s;

    float best = 3.4e38f; int bidx = 0;
    for (int wi = w; wi < 17; wi += 4) {
        int n = wi * 64 + lane;
        if (n < NCOL) {
            const float4* br = (const float4*)(book + (size_t)n * EDIM);
            float c0 = 0.f, c1 = 0.f, c2 = 0.f, c3 = 0.f;
            #pragma unroll 8
            for (int k = 0; k < 64; k++) {
                float4 bo = br[k]; float4 za = zr[k];
                c0 = fmaf(za.x, bo.x, c0); c1 = fmaf(za.y, bo.y, c1);
                c2 = fmaf(za.z, bo.z, c2); c3 = fmaf(za.w, bo.w, c3);
            }
            float cr = (c0 + c1) + (c2 + c3);
            float d0 = (zsq + bsq[n]) - 2.0f * cr;
            if (d0 < best || (d0 == best && n < bidx)) { best = d0; bidx = n; }
        }
    }
    #pragma unroll
    for (int off = 32; off; off >>= 1) {
        float ob = __shfl_xor(best, off, 64);
        int   oi = __shfl_xor(bidx, off, 64);
        if (ob < best || (ob == best && oi < bidx)) { best = ob; bidx = oi; }
    }
    __shared__ float sb[4]; __shared__ int si[4];
    if (lane == 0) { sb[w] = best; si[w] = bidx; }
    __syncthreads();
    if (tid != 0) return;

    best = sb[0]; bidx = si[0];
    for (int i = 1; i < 4; i++) {
        float vv = sb[i]; int ii = si[i];
        if (vv < best || (vv == best && ii < bidx)) { best = vv; bidx = ii; }
    }
    wind[(size_t)b * TT] = min(bidx, N_E - 1);
}

/* ---------------- K2b: serial scan, 4-way SPECULATIVE groups -------------------
   R6/R7 falsified registers & prefetch distance; invariant ~150cyc/step points
   at the per-step VALU(readlane)<->SALU ping-pong. Fix: at each 4-step group
   start rel is known; issue all 10 readlanes Q[j][a]=q[t+j][min(rel+a,63)]
   up-front (independent, pipelined), then resolve 4 steps in pure SALU
   (a = cumulative advances, qsel by a, stay = kk<=qsel). Cross-pipe handoff
   once per group. Columns proven identical to R5 semantics incl. 1023 cap.
   CH=28: 2-chunk window drift 56, +3 speculation = 59 < 64.                   */
#define CH 28
__global__ __attribute__((amdgpu_waves_per_eu(1, 1)))
__launch_bounds__(64) void k2b_scan(const short* __restrict__ q16,
                                    int* __restrict__ wind) {
    int b = blockIdx.x, lane = threadIdx.x;
    size_t ibase = (size_t)b * TT;
    int ind = wind[ibase];
    const short* qb = q16 + (size_t)b * TT * 1024;

    int cur[CH], nxt[CH];
    int kk = 0;
    int cb = min(ind, 960);

    #pragma unroll
    for (int j = 0; j < CH; j++)
        cur[j] = qb[(size_t)(1 + j) * 1024 + cb + lane];

    int t = 1;
    for (int c = 0; c < 37; c++) {
        int cbn = min(ind, 960);
        if (c < 36) {
            #pragma unroll
            for (int j = 0; j < CH; j++) {
                int tn = t + CH + j; tn = tn < 1024 ? tn : 1023;
                nxt[j] = qb[(size_t)tn * 1024 + cbn + lane];
            }
        }
        int packed = 0;
        int rel = ind - cb;
        #pragma unroll
        for (int g = 0; g < CH / 4; g++) {
            int l0 = rel;
            int l1 = rel + 1 < 63 ? rel + 1 : 63;
            int l2 = rel + 2 < 63 ? rel + 2 : 63;
            int l3 = rel + 3 < 63 ? rel + 3 : 63;
            int q00 = __builtin_amdgcn_readlane(cur[g * 4 + 0], l0);
            int q10 = __builtin_amdgcn_readlane(cur[g * 4 + 1], l0);
            int q11 = __builtin_amdgcn_readlane(cur[g * 4 + 1], l1);
            int q20 = __builtin_amdgcn_readlane(cur[g * 4 + 2], l0);
            int q21 = __builtin_amdgcn_readlane(cur[g * 4 + 2], l1);
            int q22 = __builtin_amdgcn_readlane(cur[g * 4 + 2], l2);
            int q30 = __builtin_amdgcn_readlane(cur[g * 4 + 3], l0);
            int q31 = __builtin_amdgcn_readlane(cur[g * 4 + 3], l1);
            int q32 = __builtin_amdgcn_readlane(cur[g * 4 + 3], l2);
            int q33 = __builtin_amdgcn_readlane(cur[g * 4 + 3], l3);
            int indg = ind;
            /* step 0 */
            bool s0 = (kk <= q00);
            kk = s0 ? kk + 1 : 0;
            int a = s0 ? 0 : 1;
            int i0 = indg + a; i0 = i0 < 1023 ? i0 : 1023;
            packed = (lane == g * 4 + 0) ? i0 : packed;
            /* step 1 */
            int qs1 = (a == 0) ? q10 : q11;
            bool s1 = (kk <= qs1);
            kk = s1 ? kk + 1 : 0;
            a = s1 ? a : a + 1;
            int i1 = indg + a; i1 = i1 < 1023 ? i1 : 1023;
            packed = (lane == g * 4 + 1) ? i1 : packed;
            /* step 2 */
            int qs2 = (a == 0) ? q20 : ((a == 1) ? q21 : q22);
            bool s2 = (kk <= qs2);
            kk = s2 ? kk + 1 : 0;
            a = s2 ? a : a + 1;
            int i2 = indg + a; i2 = i2 < 1023 ? i2 : 1023;
            packed = (lane == g * 4 + 2) ? i2 : packed;
            /* step 3 */
            int qs3 = (a == 0) ? q30 : ((a == 1) ? q31 : ((a == 2) ? q32 : q33));
            bool s3 = (kk <= qs3);
            kk = s3 ? kk + 1 : 0;
            a = s3 ? a : a + 1;
            int i3 = indg + a; i3 = i3 < 1023 ? i3 : 1023;
            packed = (lane == g * 4 + 3) ? i3 : packed;

            ind = i3;
            rel = ind - cb;
        }
        if (lane < CH && (t + lane) < 1024) wind[ibase + t + lane] = packed;
        #pragma unroll
        for (int j = 0; j < CH; j++) cur[j] = nxt[j];
        cb = cbn;
        t += CH;
    }
}

/* ---------------- K3: per-row hinge-loss partial + z_q gather + idx emit ------ */
__global__ __launch_bounds__(256) void k3_loss_zq(const float* __restrict__ e,
                                                  const int* __restrict__ wind,
                                                  const float* __restrict__ book,
                                                  float* __restrict__ part,
                                                  float* __restrict__ out) {
    int rIdx = blockIdx.x, tid = threadIdx.x;
    int ind = wind[rIdx];
    const float* er = e + (size_t)rIdx * NPAD;
    float eind = er[ind];
    float p = 0.0f;
    for (int n = tid; n < NCOL; n += 256) {
        float v = eind - er[n] + EPSC;
        p += v > 0.0f ? v : 0.0f;
    }
    __shared__ float sd[256];
    sd[tid] = p; __syncthreads();
    for (int s = 128; s > 0; s >>= 1) { if (tid < s) sd[tid] += sd[tid + s]; __syncthreads(); }
    if (tid == 0) { part[rIdx] = sd[0]; out[OUT_IDX + rIdx] = (float)ind; }
    out[(size_t)rIdx * 256 + tid] = book[(size_t)ind * EDIM + tid];   /* z_q */
}

/* ---------------- K4: final loss reduce + v ---------------- */
__global__ __launch_bounds__(256) void k4_final(const float* __restrict__ part,
                                                const int* __restrict__ wind,
                                                float* __restrict__ out) {
    int tid = threadIdx.x;
    float s = 0.0f;
    for (int i = tid; i < NROW; i += 256) s += part[i];
    __shared__ float sd[256];
    sd[tid] = s; __syncthreads();
    for (int st = 128; st > 0; st >>= 1) { if (tid < st) sd[tid] += sd[tid + st]; __syncthreads(); }
    if (tid == 0) {
        int mn = wind[0], mx = wind[TT - 1];
        for (int b = 1; b < BB; b++) {
            mn = min(mn, wind[(size_t)b * TT]);
            mx = max(mx, wind[(size_t)b * TT + TT - 1]);
        }
        out[OUT_LOSS] = 1.25f * sd[0] / ((float)NROW * (float)NCOL);
        out[OUT_V] = (float)(mx - mn);
    }
}

extern "C" void kernel_launch(void* const* d_in, const int* in_sizes, int n_in,
                              void* d_out, int out_size, void* d_ws, size_t ws_size,
                              hipStream_t stream) {
    const float* z    = (const float*)d_in[0];
    const float* book = (const float*)d_in[1];
    char* ws = (char*)d_ws;
    unsigned short* zb = (unsigned short*)(ws + WS_ZB);
    unsigned short* bb = (unsigned short*)(ws + WS_BBF);
    float* bsq  = (float*)(ws + WS_BSQ);
    float* e    = (float*)(ws + WS_E);
    int*   wind = (int*)(ws + WS_IND);
    float* part = (float*)(ws + WS_PART);
    short* q16  = (short*)(ws + WS_Q);
    float* out  = (float*)d_out;

    hipLaunchKernelGGL(k0_prep,    dim3(4096 + 1152), dim3(256), 0, stream, z, book, zb, bb, bsq);
    hipLaunchKernelGGL(k1_gemm,    dim3(128, 9),      dim3(256), 0, stream, zb, bb, bsq, e);
    hipLaunchKernelGGL(k1b_q,      dim3(NROW),        dim3(256), 0, stream, e, q16);
    hipLaunchKernelGGL(k2a_argmin, dim3(16),          dim3(256), 0, stream, z, book, bsq, wind);
    hipLaunchKernelGGL(k2b_scan,   dim3(16),          dim3(64),  0, stream, q16, wind);
    hipLaunchKernelGGL(k3_loss_zq, dim3(16384),       dim3(256), 0, stream, e, wind, book, part, out);
    hipLaunchKernelGGL(k4_final,   dim3(1),           dim3(256), 0, stream, part, wind, out);
}

// Round 9
// 266.668 us; speedup vs baseline: 1.0910x; 1.0910x over previous
//
#include <hip/hip_runtime.h>

#define N_E   1024
#define EDIM  256
#define BB    16
#define TT    1024
#define NROW  (BB*TT)        /* 16384 */
#define NCOL  1025
#define NPAD  1152           /* 9*128 */
#define PERS  (0.1f/1024.0f)
#define EPSC  (1e-6f/1024.0f)

/* d_out layout (float32): z_q [0,4194304) | loss 4194304 | ind [4194305,+16384) | v 4210689 */
#define OUT_LOSS 4194304
#define OUT_IDX  4194305
#define OUT_V    4210689

/* ws layout (bytes) — offsets kept from prior rounds (regions shrank, safe) */
#define WS_ZB   0ull                               /* 16384*256*2  = 8388608  */
#define WS_BBF  8388608ull                         /* 1152*256*2   = 589824   */
#define WS_BSQ  8978432ull                         /* 1152*4       = 4608     */
#define WS_E    8983552ull                         /* 16384*1152*2 = 37748736 (bf16 now) */
#define WS_IND  84481024ull                        /* 16384*4                 */
#define WS_PART 84546560ull                        /* 16384*4                 */
#define WS_Q    84612096ull                        /* 16384*1024*2 = 33554432 */

typedef __attribute__((ext_vector_type(8))) short short8;
typedef __attribute__((ext_vector_type(4))) float floatx4;

__device__ __forceinline__ unsigned short f2bf(float f) {
    unsigned int u = __float_as_uint(f);
    u = (u + 0x7fffu + ((u >> 16) & 1u)) >> 16;   /* RNE */
    return (unsigned short)u;
}
__device__ __forceinline__ float bf2f(unsigned short h) {
    return __uint_as_float(((unsigned int)h) << 16);
}

/* ---------------- K0: convert z/book -> bf16, compute bsq (fp32) ---------------- */
__global__ __launch_bounds__(256) void k0_prep(const float* __restrict__ z,
                                               const float* __restrict__ book,
                                               unsigned short* __restrict__ zb,
                                               unsigned short* __restrict__ bb,
                                               float* __restrict__ bsq) {
    int bx = blockIdx.x, tid = threadIdx.x;
    if (bx < 4096) {                     /* z: 4096 blocks * 256 thr * 4 floats */
        float4 v = ((const float4*)z)[bx * 256 + tid];
        size_t o = ((size_t)bx * 256 + tid) * 4;
        zb[o + 0] = f2bf(v.x); zb[o + 1] = f2bf(v.y);
        zb[o + 2] = f2bf(v.z); zb[o + 3] = f2bf(v.w);
    } else {                             /* book rows, padded to 1152 with zeros */
        int row = bx - 4096;             /* 0..1151 */
        float v = (row < NCOL) ? book[(size_t)row * EDIM + tid] : 0.0f;
        bb[(size_t)row * EDIM + tid] = f2bf(v);
        __shared__ float sd[256];
        sd[tid] = v * v;
        __syncthreads();
        for (int s = 128; s > 0; s >>= 1) { if (tid < s) sd[tid] += sd[tid + s]; __syncthreads(); }
        if (tid == 0) bsq[row] = sd[0];
    }
}

/* ---------------- K1: e[r][n] = bsq[n] - 2 * dot(z[r], book[n]), stored bf16 ---- */
__global__ __launch_bounds__(256) void k1_gemm(const unsigned short* __restrict__ zb,
                                               const unsigned short* __restrict__ bb,
                                               const float* __restrict__ bsq,
                                               unsigned short* __restrict__ e) {
    int tid = threadIdx.x;
    int lane = tid & 63, w = tid >> 6;
    int mBase = blockIdx.x * 128 + (w >> 1) * 64;
    int nBase = blockIdx.y * 128 + (w & 1) * 64;
    int r = lane & 15, q = lane >> 4;

    floatx4 acc[4][4];
    #pragma unroll
    for (int i = 0; i < 4; i++)
        #pragma unroll
        for (int j = 0; j < 4; j++) acc[i][j] = (floatx4){0.f, 0.f, 0.f, 0.f};

    const short8* A = (const short8*)zb;   /* row stride 256 bf16 = 32 short8 */
    const short8* Bm = (const short8*)bb;

    #pragma unroll
    for (int ks = 0; ks < 8; ks++) {
        int k8 = ks * 4 + q;               /* short8 index in row: (ks*32+q*8)/8 */
        short8 a[4], b[4];
        #pragma unroll
        for (int i = 0; i < 4; i++) a[i] = A[(size_t)(mBase + i * 16 + r) * 32 + k8];
        #pragma unroll
        for (int j = 0; j < 4; j++) b[j] = Bm[(size_t)(nBase + j * 16 + r) * 32 + k8];
        #pragma unroll
        for (int i = 0; i < 4; i++)
            #pragma unroll
            for (int j = 0; j < 4; j++)
                acc[i][j] = __builtin_amdgcn_mfma_f32_16x16x32_bf16(a[i], b[j], acc[i][j], 0, 0, 0);
    }

    float bsql[4];
    #pragma unroll
    for (int j = 0; j < 4; j++) bsql[j] = bsq[nBase + j * 16 + r];

    #pragma unroll
    for (int i = 0; i < 4; i++)
        #pragma unroll
        for (int rr = 0; rr < 4; rr++) {
            int m = mBase + i * 16 + q * 4 + rr;
            unsigned short* erow = e + (size_t)m * NPAD;
            #pragma unroll
            for (int j = 0; j < 4; j++)
                erow[nBase + j * 16 + r] = f2bf(fmaf(-2.0f, acc[i][j][rr], bsql[j]));
        }
}

/* ---------------- K1b: q16[row][c] = clamp(trunc((e[c+1]-e[c])/P)), from bf16 e --
   col 1023 forced to 0 (reference compares ind=1023 with itself -> m=0).
   256 thr x 4 cols each; ushort4 + 1 scalar load; short4 store.               */
__global__ __launch_bounds__(256) void k1b_q(const unsigned short* __restrict__ e,
                                             short* __restrict__ q16) {
    int row = blockIdx.x, tid = threadIdx.x;
    const unsigned short* er = e + (size_t)row * NPAD;
    int c = tid * 4;
    ushort4 ev = *(const ushort4*)(er + c);
    unsigned short e4 = er[c + 4];                  /* c+4 <= 1024 < NPAD, safe */
    const float QS = 1.0f / PERS;
    float f0 = bf2f(ev.x), f1 = bf2f(ev.y), f2 = bf2f(ev.z), f3 = bf2f(ev.w);
    float f4 = bf2f(e4);
    short qv[4];
    float m0 = (f1 - f0) * QS, m1 = (f2 - f1) * QS, m2 = (f3 - f2) * QS, m3 = (f4 - f3) * QS;
    qv[0] = (short)((m0 >= 0.0f) ? min((int)m0, 1023) : -1);
    qv[1] = (short)((m1 >= 0.0f) ? min((int)m1, 1023) : -1);
    qv[2] = (short)((m2 >= 0.0f) ? min((int)m2, 1023) : -1);
    qv[3] = (short)((m3 >= 0.0f) ? min((int)m3, 1023) : -1);
    if (c + 3 == 1023) qv[3] = 0;
    *(short4*)(q16 + (size_t)row * 1024 + c) = make_short4(qv[0], qv[1], qv[2], qv[3]);
}

/* ---------------- K2a: fp32 argmin of d[b,0,:] (reference-style) ---------------- */
__global__ __launch_bounds__(256) void k2a_argmin(const float* __restrict__ z,
                                                  const float* __restrict__ book,
                                                  const float* __restrict__ bsq,
                                                  int* __restrict__ wind) {
    int b = blockIdx.x, tid = threadIdx.x;
    int lane = tid & 63, w = tid >> 6;

    const float4* zr = (const float4*)(z + (size_t)b * TT * EDIM);  /* t=0 row */
    float4 zv = zr[lane];
    float s = zv.x * zv.x + zv.y * zv.y + zv.z * zv.z + zv.w * zv.w;
    #pragma unroll
    for (int off = 32; off; off >>= 1) s += __shfl_xor(s, off, 64);
    float zsq = s;

    float best = 3.4e38f; int bidx = 0;
    for (int wi = w; wi < 17; wi += 4) {
        int n = wi * 64 + lane;
        if (n < NCOL) {
            const float4* br = (const float4*)(book + (size_t)n * EDIM);
            float c0 = 0.f, c1 = 0.f, c2 = 0.f, c3 = 0.f;
            #pragma unroll 8
            for (int k = 0; k < 64; k++) {
                float4 bo = br[k]; float4 za = zr[k];
                c0 = fmaf(za.x, bo.x, c0); c1 = fmaf(za.y, bo.y, c1);
                c2 = fmaf(za.z, bo.z, c2); c3 = fmaf(za.w, bo.w, c3);
            }
            float cr = (c0 + c1) + (c2 + c3);
            float d0 = (zsq + bsq[n]) - 2.0f * cr;
            if (d0 < best || (d0 == best && n < bidx)) { best = d0; bidx = n; }
        }
    }
    #pragma unroll
    for (int off = 32; off; off >>= 1) {
        float ob = __shfl_xor(best, off, 64);
        int   oi = __shfl_xor(bidx, off, 64);
        if (ob < best || (ob == best && oi < bidx)) { best = ob; bidx = oi; }
    }
    __shared__ float sb[4]; __shared__ int si[4];
    if (lane == 0) { sb[w] = best; si[w] = bidx; }
    __syncthreads();
    if (tid != 0) return;

    best = sb[0]; bidx = si[0];
    for (int i = 1; i < 4; i++) {
        float vv = sb[i]; int ii = si[i];
        if (vv < best || (vv == best && ii < bidx)) { best = vv; bidx = ii; }
    }
    wind[(size_t)b * TT] = min(bidx, N_E - 1);
}

/* ---------------- K2b: serial scan on q16, ONE wave per batch row --------------
   CHAMPION (R5, 63.5us): 1 readlane/step, double-buffer chunks of 31.
   R6-R8 falsified: registers (VGPR 40 vs 132 identical), prefetch distance
   (3-buf worse), speculation (2.5 readlanes/step much worse). Cost tracks the
   per-step VALU<->SALU handoff; this structure is the measured minimum.      */
__global__ __launch_bounds__(64, 1) void k2b_scan(const short* __restrict__ q16,
                                                  int* __restrict__ wind) {
    int b = blockIdx.x, lane = threadIdx.x;
    size_t ibase = (size_t)b * TT;
    int ind = wind[ibase];               /* same addr all lanes: broadcast load */
    int kk = 0;

    const short* qb = q16 + (size_t)b * TT * 1024;
    int cur[31], nxt[31];

    int cb = min(ind, 960);
    #pragma unroll
    for (int j = 0; j < 31; j++)
        cur[j] = qb[(size_t)(1 + j) * 1024 + cb + lane];

    int t = 1;
    for (int c = 0; c < 33; c++) {
        int cbn = min(ind, 960);         /* window base for chunk c+1 (<=62 drift over 2 chunks) */
        if (c < 32) {
            #pragma unroll
            for (int j = 0; j < 31; j++) {
                int tn = t + 31 + j; tn = tn < 1024 ? tn : 1023;
                nxt[j] = qb[(size_t)tn * 1024 + cbn + lane];
            }
        }
        int packed = 0;
        #pragma unroll
        for (int j = 0; j < 31; j++) {
            int rel = ind - cb;
            int qv = __builtin_amdgcn_readlane(cur[j], rel);
            bool stay = (kk <= qv);
            int ip1 = ind + 1; ip1 = ip1 < 1023 ? ip1 : 1023;
            ind = stay ? ind : ip1;
            kk  = stay ? kk + 1 : 0;
            packed = (lane == j) ? ind : packed;
        }
        if (lane < 31 && (t + lane) < 1024) wind[ibase + t + lane] = packed;
        #pragma unroll
        for (int j = 0; j < 31; j++) cur[j] = nxt[j];
        cb = cbn;
        t += 31;
    }
}

/* ---------------- K3: per-row hinge-loss partial + z_q gather + idx emit ------
   e is bf16 now: half the read traffic of fp32.                               */
__global__ __launch_bounds__(256) void k3_loss_zq(const unsigned short* __restrict__ e,
                                                  const int* __restrict__ wind,
                                                  const float* __restrict__ book,
                                                  float* __restrict__ part,
                                                  float* __restrict__ out) {
    int rIdx = blockIdx.x, tid = threadIdx.x;
    int ind = wind[rIdx];
    const unsigned short* er = e + (size_t)rIdx * NPAD;
    float eind = bf2f(er[ind]);
    float p = 0.0f;
    for (int n = tid; n < NCOL; n += 256) {
        float v = eind - bf2f(er[n]) + EPSC;
        p += v > 0.0f ? v : 0.0f;
    }
    __shared__ float sd[256];
    sd[tid] = p; __syncthreads();
    for (int s = 128; s > 0; s >>= 1) { if (tid < s) sd[tid] += sd[tid + s]; __syncthreads(); }
    if (tid == 0) { part[rIdx] = sd[0]; out[OUT_IDX + rIdx] = (float)ind; }
    out[(size_t)rIdx * 256 + tid] = book[(size_t)ind * EDIM + tid];   /* z_q */
}

/* ---------------- K4: final loss reduce + v ---------------- */
__global__ __launch_bounds__(256) void k4_final(const float* __restrict__ part,
                                                const int* __restrict__ wind,
                                                float* __restrict__ out) {
    int tid = threadIdx.x;
    float s = 0.0f;
    for (int i = tid; i < NROW; i += 256) s += part[i];
    __shared__ float sd[256];
    sd[tid] = s; __syncthreads();
    for (int st = 128; st > 0; st >>= 1) { if (tid < st) sd[tid] += sd[tid + st]; __syncthreads(); }
    if (tid == 0) {
        int mn = wind[0], mx = wind[TT - 1];
        for (int b = 1; b < BB; b++) {
            mn = min(mn, wind[(size_t)b * TT]);
            mx = max(mx, wind[(size_t)b * TT + TT - 1]);
        }
        out[OUT_LOSS] = 1.25f * sd[0] / ((float)NROW * (float)NCOL);
        out[OUT_V] = (float)(mx - mn);
    }
}

extern "C" void kernel_launch(void* const* d_in, const int* in_sizes, int n_in,
                              void* d_out, int out_size, void* d_ws, size_t ws_size,
                              hipStream_t stream) {
    const float* z    = (const float*)d_in[0];
    const float* book = (const float*)d_in[1];
    char* ws = (char*)d_ws;
    unsigned short* zb = (unsigned short*)(ws + WS_ZB);
    unsigned short* bb = (unsigned short*)(ws + WS_BBF);
    float* bsq  = (float*)(ws + WS_BSQ);
    unsigned short* e = (unsigned short*)(ws + WS_E);
    int*   wind = (int*)(ws + WS_IND);
    float* part = (float*)(ws + WS_PART);
    short* q16  = (short*)(ws + WS_Q);
    float* out  = (float*)d_out;

    hipLaunchKernelGGL(k0_prep,    dim3(4096 + 1152), dim3(256), 0, stream, z, book, zb, bb, bsq);
    hipLaunchKernelGGL(k1_gemm,    dim3(128, 9),      dim3(256), 0, stream, zb, bb, bsq, e);
    hipLaunchKernelGGL(k1b_q,      dim3(NROW),        dim3(256), 0, stream, e, q16);
    hipLaunchKernelGGL(k2a_argmin, dim3(16),          dim3(256), 0, stream, z, book, bsq, wind);
    hipLaunchKernelGGL(k2b_scan,   dim3(16),          dim3(64),  0, stream, q16, wind);
    hipLaunchKernelGGL(k3_loss_zq, dim3(16384),       dim3(256), 0, stream, e, wind, book, part, out);
    hipLaunchKernelGGL(k4_final,   dim3(1),           dim3(256), 0, stream, part, wind, out);
}